// Round 1
// baseline (381.872 us; speedup 1.0000x reference)
//
#include <hip/hip_runtime.h>
#include <hip/hip_bf16.h>

// ---------------- constants ----------------
#define BATCH   64
#define LSIG    240000
#define WIN     400
#define SHIFT   160
#define NFR     1498        // 1 + (240000-400)/160
#define NMEL    80
#define NBIN    200         // win/2 ; bin 200 (Nyquist) has zero bank weight
#define NF      8           // frames per block
#define MAXW    16          // max nonzero mel-bank width (true max ~14)

// ---------------- precomputed tables (device globals) ----------------
__device__ float g_win[WIN];                 // Hann (denominator 399), f64-computed
__device__ float g_tw1[11][20][2];           // e^{-2pi i r t1 / 20}, r=0..10
__device__ float g_tw2[NBIN][20][2];         // e^{-2pi i k t2 / 400}
__device__ int   g_melStart[NMEL];
__device__ float g_melW[NMEL][MAXW];

__global__ void init_tables_kernel() {
    const int tid = threadIdx.x;              // 1 block x 256
    const double PI = 3.14159265358979323846;

    for (int t = tid; t < WIN; t += 256)
        g_win[t] = (float)(0.5 - 0.5 * cos(2.0 * PI * (double)t / 399.0));

    for (int i = tid; i < 11 * 20; i += 256) {
        int r = i / 20, t1 = i % 20;
        double th = -2.0 * PI * (double)(r * t1) / 20.0;
        g_tw1[r][t1][0] = (float)cos(th);
        g_tw1[r][t1][1] = (float)sin(th);
    }
    for (int i = tid; i < NBIN * 20; i += 256) {
        int k = i / 20, t2 = i % 20;
        double th = -2.0 * PI * (double)(k * t2) / 400.0;
        g_tw2[k][t2][0] = (float)cos(th);
        g_tw2[k][t2][1] = (float)sin(th);
    }
    if (tid < NMEL) {
        int m = tid;
        double mlow  = 1127.0 * log(1.0 + 20.0   / 700.0);
        double mhigh = 1127.0 * log(1.0 + 8000.0 / 700.0);
        double d     = (mhigh - mlow) / (double)(NMEL + 1);
        double left  = mlow + (double)m * d;
        double right = left + 2.0 * d;
        for (int j = 0; j < MAXW; j++) g_melW[m][j] = 0.0f;
        int start = 0; bool found = false;
        for (int k = 0; k < NBIN; k++) {
            double mel = 1127.0 * log(1.0 + (40.0 * (double)k) / 700.0);
            double up = (mel - left) / d, down = (right - mel) / d;
            double w = fmax(0.0, fmin(up, down));
            if (w > 0.0) {
                if (!found) { start = k; found = true; }
                int j = k - start;
                if (j < MAXW) g_melW[m][j] = (float)w;
            }
        }
        g_melStart[m] = start;
    }
}

// ---------------- main fbank kernel ----------------
// block: 256 threads, handles NF consecutive frames of one batch row.
__global__ __launch_bounds__(256)
void fbank_kernel(const float* __restrict__ x, const float* __restrict__ norm,
                  float* __restrict__ out) {
    const int ft = blockIdx.x;
    const int b  = blockIdx.y;
    const int f0 = ft * NF;
    const int nf = min(NF, NFR - f0);

    __shared__ float xseg[(NF - 1) * SHIFT + WIN];      // 1520 f
    __shared__ float ys[NF][WIN];                       // 3200 f
    __shared__ float S[NF][20][11][2];                  // 3520 f
    __shared__ float spec[NF][NBIN + MAXW];             // 1728 f   (pad zeros)

    const float* xb = x + (size_t)b * LSIG + (size_t)f0 * SHIFT;
    const int seglen = (nf - 1) * SHIFT + WIN;
    for (int i = threadIdx.x; i < seglen; i += 256) xseg[i] = xb[i];
    __syncthreads();

    // stage 0: preemph + window
    const int tot = nf * WIN;
    for (int i = threadIdx.x; i < tot; i += 256) {
        int f = i / WIN, t = i - f * WIN;
        float v;
        if (t == 0) v = 0.0f;   // w[0] == 0 exactly; matches (x0-0.97*x0)*0
        else v = (xseg[f * SHIFT + t] - 0.97f * xseg[f * SHIFT + t - 1]) * g_win[t];
        ys[f][t] = v;
    }
    __syncthreads();

    // stage 1: 20-point real DFTs over t1 (stride-20 samples), r = 0..10
    const int pairs = nf * 20;
    for (int p = threadIdx.x; p < pairs; p += 256) {
        int f = p / 20, t2 = p - f * 20;
        float yr[20];
#pragma unroll
        for (int t1 = 0; t1 < 20; t1++) yr[t1] = ys[f][t2 + 20 * t1];
#pragma unroll
        for (int r = 0; r <= 10; r++) {
            float ar = 0.0f, ai = 0.0f;
#pragma unroll
            for (int t1 = 0; t1 < 20; t1++) {
                float c = g_tw1[r][t1][0], s = g_tw1[r][t1][1];
                ar = fmaf(yr[t1], c, ar);
                ai = fmaf(yr[t1], s, ai);
            }
            S[f][t2][r][0] = ar;
            S[f][t2][r][1] = ai;
        }
    }
    __syncthreads();

    // stage 2: combine with twiddles; thread = bin k, loops frames (tw in regs)
    {
        const int k = threadIdx.x;
        if (k < NBIN) {
            float twc[20], tws[20];
#pragma unroll
            for (int t2 = 0; t2 < 20; t2++) {
                twc[t2] = g_tw2[k][t2][0];
                tws[t2] = g_tw2[k][t2][1];
            }
            int r = k % 20;
            bool cj = (r > 10);
            int rp = cj ? 20 - r : r;
            float sgn = cj ? -1.0f : 1.0f;
            for (int f = 0; f < nf; f++) {
                float xr = 0.0f, xi = 0.0f;
#pragma unroll
                for (int t2 = 0; t2 < 20; t2++) {
                    float sre = S[f][t2][rp][0];
                    float sim = S[f][t2][rp][1] * sgn;
                    xr = fmaf(twc[t2], sre, fmaf(-tws[t2], sim, xr));
                    xi = fmaf(twc[t2], sim, fmaf(tws[t2], sre, xi));
                }
                spec[f][k] = xr * xr + xi * xi;
            }
        } else if (k < NBIN + MAXW) {
            for (int f = 0; f < nf; f++) spec[f][k] = 0.0f;  // zero pad for mel taps
        }
    }
    __syncthreads();

    // stage 3: sparse mel + log + normalizer, coalesced store
    const int outs = nf * NMEL;
    for (int o = threadIdx.x; o < outs; o += 256) {
        int f = o / NMEL, m = o - f * NMEL;
        int ks = g_melStart[m];
        float acc = 0.0f;
#pragma unroll
        for (int j = 0; j < MAXW; j++)
            acc = fmaf(g_melW[m][j], spec[f][ks + j], acc);
        float mel = fmaxf(acc, 2.2204460492503131e-16f);
        float v = logf(mel) * norm[m];
        out[((size_t)b * NFR + (f0 + f)) * NMEL + m] = v;
    }
}

// ---------------- masked mean subtraction ----------------
// T_ = int(T_b / (maxT/80)); subtract per-(b,m) mean of first T_ frames.
__global__ void meansub_kernel(float* __restrict__ out, const int* __restrict__ T) {
    const int b = blockIdx.x;
    int maxT = T[0];
    for (int i = 1; i < BATCH; i++) maxT = max(maxT, T[i]);
    float ds = (float)maxT / (float)NMEL;          // f32, matches numpy
    int tb = (int)((float)T[b] / ds);              // trunc, matches astype(int32)
    int m = threadIdx.x;
    if (m >= NMEL) return;
    float* p = out + (size_t)b * NFR * NMEL + m;
    float sum = 0.0f;
    for (int f = 0; f < tb; f++) sum += p[(size_t)f * NMEL];
    float mean = sum / (float)max(tb, 1);
    for (int f = 0; f < tb; f++) p[(size_t)f * NMEL] -= mean;
}

// ---------------- launcher ----------------
extern "C" void kernel_launch(void* const* d_in, const int* in_sizes, int n_in,
                              void* d_out, int out_size, void* d_ws, size_t ws_size,
                              hipStream_t stream) {
    const float* x    = (const float*)d_in[0];
    const int*   T    = (const int*)d_in[1];
    const float* norm = (const float*)d_in[2];
    float* out = (float*)d_out;

    init_tables_kernel<<<1, 256, 0, stream>>>();

    dim3 grid((NFR + NF - 1) / NF, BATCH);
    fbank_kernel<<<grid, 256, 0, stream>>>(x, norm, out);

    meansub_kernel<<<BATCH, 128, 0, stream>>>(out, T);
}

// Round 2
// 227.571 us; speedup vs baseline: 1.6780x; 1.6780x over previous
//
#include <hip/hip_runtime.h>
#include <hip/hip_bf16.h>

// ---------------- constants ----------------
#define BATCH   64
#define LSIG    240000
#define WIN     400
#define SHIFT   160
#define NFR     1498        // 1 + (240000-400)/160
#define NMEL    80
#define NBIN    200         // win/2 ; Nyquist bin has zero bank weight
#define NF      8           // frames per block
#define MAXW    14          // max nonzero mel-bank width (true max 12-13)
#define SPECW   (NBIN + MAXW)

// ---------------- precomputed tables (device globals) ----------------
__device__ float g_win[WIN];                 // Hann (denominator 399), f64-computed
__device__ float g_tw1[11][20][2];           // e^{-2pi i r t1 / 20}, r=0..10
__device__ float g_tw2[NBIN][20][2];         // e^{-2pi i k t2 / 400}
__device__ int   g_melStart[NMEL];
__device__ float g_melW[NMEL][MAXW];

__global__ void init_tables_kernel() {
    const int tid = threadIdx.x;              // 1 block x 256
    const double PI = 3.14159265358979323846;
    __shared__ double melf[NBIN];

    for (int t = tid; t < WIN; t += 256)
        g_win[t] = (float)(0.5 - 0.5 * cos(2.0 * PI * (double)t / 399.0));

    for (int i = tid; i < 11 * 20; i += 256) {
        int r = i / 20, t1 = i % 20;
        double th = -2.0 * PI * (double)(r * t1) / 20.0;
        g_tw1[r][t1][0] = (float)cos(th);
        g_tw1[r][t1][1] = (float)sin(th);
    }
    for (int i = tid; i < NBIN * 20; i += 256) {
        int k = i / 20, t2 = i % 20;
        double th = -2.0 * PI * (double)(k * t2) / 400.0;
        g_tw2[k][t2][0] = (float)cos(th);
        g_tw2[k][t2][1] = (float)sin(th);
    }
    // one double-log per bin, shared by all banks (was 200 logs PER bank)
    for (int k = tid; k < NBIN; k += 256)
        melf[k] = 1127.0 * log(1.0 + (40.0 * (double)k) / 700.0);
    __syncthreads();

    if (tid < NMEL) {
        int m = tid;
        double mlow  = 1127.0 * log(1.0 + 20.0   / 700.0);
        double mhigh = 1127.0 * log(1.0 + 8000.0 / 700.0);
        double d     = (mhigh - mlow) / (double)(NMEL + 1);
        double inv_d = 1.0 / d;
        double left  = mlow + (double)m * d;
        double right = left + 2.0 * d;
        for (int j = 0; j < MAXW; j++) g_melW[m][j] = 0.0f;
        int start = 0; bool found = false;
        for (int k = 0; k < NBIN; k++) {
            double up = (melf[k] - left) * inv_d, down = (right - melf[k]) * inv_d;
            double w = fmax(0.0, fmin(up, down));
            if (w > 0.0) {
                if (!found) { start = k; found = true; }
                int j = k - start;
                if (j < MAXW) g_melW[m][j] = (float)w;
            }
        }
        g_melStart[m] = start;
    }
}

// ---------------- main fbank kernel ----------------
// block: 256 threads, NF consecutive frames of one batch row.
// LDS plan (floats):  [0 .. 3520)  S[NF][11][20][2]
//                     [3520 .. )   xseg (load..stage1)  ALIASED WITH spec (stage2..stage3)
__global__ __launch_bounds__(256, 6)
void fbank_kernel(const float* __restrict__ x, const float* __restrict__ norm,
                  float* __restrict__ out) {
    const int ft = blockIdx.x;
    const int b  = blockIdx.y;
    const int f0 = ft * NF;
    const int nf = min(NF, NFR - f0);

    __shared__ __align__(16) float smem[3520 + NF * SPECW];  // 3520 + 1712 floats
    float* Sb   = smem;            // [f][r][t2][2] : ((f*11 + r)*20 + t2)*2
    float* xseg = smem + 3520;     // (NF-1)*SHIFT + WIN = 1520 floats
    float* spec = smem + 3520;     // [NF][SPECW]         = 1712 floats (aliases xseg)

    const float* xb = x + (size_t)b * LSIG + (size_t)f0 * SHIFT;
    const int seglen = (nf - 1) * SHIFT + WIN;
    for (int i = threadIdx.x; i < seglen; i += 256) xseg[i] = xb[i];
    __syncthreads();

    // stage 1 (fused preemph+window): 20-point real DFTs over t1, r = 0..10
    {
        const int p = threadIdx.x;
        if (p < nf * 20) {
            const int f = p / 20, t2 = p - f * 20;
            const float* xf = xseg + f * SHIFT;
            float yr[20];
#pragma unroll
            for (int t1 = 0; t1 < 20; t1++) {
                int t = t2 + 20 * t1;
                float xc = xf[t];
                float xp = xf[t > 0 ? t - 1 : 0];   // t==0: win==0 -> result 0 anyway
                yr[t1] = (xc - 0.97f * xp) * g_win[t];
            }
#pragma unroll
            for (int r = 0; r <= 10; r++) {
                float ar = 0.0f, ai = 0.0f;
#pragma unroll
                for (int t1 = 0; t1 < 20; t1++) {
                    float c = g_tw1[r][t1][0], s = g_tw1[r][t1][1];
                    ar = fmaf(yr[t1], c, ar);
                    ai = fmaf(yr[t1], s, ai);
                }
                *(float2*)(Sb + ((f * 11 + r) * 20 + t2) * 2) = make_float2(ar, ai);
            }
        }
    }
    __syncthreads();

    // stage 2: combine; thread = bin k, loops frames (twiddles in regs).
    // Conjugate fold: power is invariant under xi -> sgn*xi, so fold sgn into sine.
    {
        const int k = threadIdx.x;
        if (k < NBIN) {
            int r = k % 20;
            bool cj = (r > 10);
            int rp = cj ? 20 - r : r;
            float sgn = cj ? -1.0f : 1.0f;
            float twc[20], s2[20];
#pragma unroll
            for (int t2 = 0; t2 < 20; t2++) {
                twc[t2] = g_tw2[k][t2][0];
                s2[t2]  = g_tw2[k][t2][1] * sgn;
            }
            for (int f = 0; f < nf; f++) {
                const float4* Sf = (const float4*)(Sb + (f * 11 + rp) * 40);
                float xr0 = 0.f, xi0 = 0.f, xr1 = 0.f, xi1 = 0.f;
#pragma unroll
                for (int q = 0; q < 10; q++) {
                    float4 v = Sf[q];            // re(2q), im(2q), re(2q+1), im(2q+1)
                    float c0 = twc[2 * q],     ss0 = s2[2 * q];
                    float c1 = twc[2 * q + 1], ss1 = s2[2 * q + 1];
                    xr0 = fmaf(c0, v.x, xr0);  xr0 = fmaf(-ss0, v.y, xr0);
                    xi0 = fmaf(ss0, v.x, xi0); xi0 = fmaf(c0,  v.y, xi0);
                    xr1 = fmaf(c1, v.z, xr1);  xr1 = fmaf(-ss1, v.w, xr1);
                    xi1 = fmaf(ss1, v.z, xi1); xi1 = fmaf(c1,  v.w, xi1);
                }
                float xr = xr0 + xr1, xi = xi0 + xi1;
                spec[f * SPECW + k] = fmaf(xr, xr, xi * xi);
            }
        } else if (k < NBIN + MAXW) {
            for (int f = 0; f < nf; f++) spec[f * SPECW + k] = 0.0f;  // pad taps
        }
    }
    __syncthreads();

    // stage 3: sparse mel + log + normalizer, coalesced store
    const int outs = nf * NMEL;
    for (int o = threadIdx.x; o < outs; o += 256) {
        int f = o / NMEL, m = o - f * NMEL;
        int ks = g_melStart[m];
        const float* sp = spec + f * SPECW + ks;
        float acc = 0.0f;
#pragma unroll
        for (int j = 0; j < MAXW; j++)
            acc = fmaf(g_melW[m][j], sp[j], acc);
        float mel = fmaxf(acc, 2.2204460492503131e-16f);
        float v = logf(mel) * norm[m];
        out[((size_t)b * NFR + (f0 + f)) * NMEL + m] = v;
    }
}

// ---------------- masked mean subtraction ----------------
__global__ __launch_bounds__(256)
void meansub_kernel(float* __restrict__ out, const int* __restrict__ T) {
    const int b = blockIdx.x;
    __shared__ float part[3][NMEL];
    __shared__ float meanSh[NMEL];

    int maxT = T[0];
    for (int i = 1; i < BATCH; i++) maxT = max(maxT, T[i]);
    float ds = (float)maxT / (float)NMEL;          // f32, matches numpy
    int tb = (int)((float)T[b] / ds);              // trunc, matches astype(int32)

    const int q = threadIdx.x / NMEL;              // 0..2 active
    const int m = threadIdx.x - q * NMEL;
    float* pb = out + (size_t)b * NFR * NMEL;

    if (q < 3) {
        float s = 0.0f;
        for (int f = q; f < tb; f += 3) s += pb[(size_t)f * NMEL + m];
        part[q][m] = s;
    }
    __syncthreads();
    if (threadIdx.x < NMEL) {
        float mean = (part[0][m] + part[1][m] + part[2][m]) / (float)max(tb, 1);
        meanSh[m] = mean;
    }
    __syncthreads();
    if (q < 3) {
        float mean = meanSh[m];
        for (int f = q; f < tb; f += 3) pb[(size_t)f * NMEL + m] -= mean;
    }
}

// ---------------- launcher ----------------
extern "C" void kernel_launch(void* const* d_in, const int* in_sizes, int n_in,
                              void* d_out, int out_size, void* d_ws, size_t ws_size,
                              hipStream_t stream) {
    const float* x    = (const float*)d_in[0];
    const int*   T    = (const int*)d_in[1];
    const float* norm = (const float*)d_in[2];
    float* out = (float*)d_out;

    init_tables_kernel<<<1, 256, 0, stream>>>();

    dim3 grid((NFR + NF - 1) / NF, BATCH);
    fbank_kernel<<<grid, 256, 0, stream>>>(x, norm, out);

    meansub_kernel<<<BATCH, 256, 0, stream>>>(out, T);
}